// Round 7
// baseline (446.132 us; speedup 1.0000x reference)
//
#include <hip/hip_runtime.h>
#include <math.h>

#define N 512
#define H 128
#define L 4
#define NUM_RBF 50
#define NMOL 16
#define SUPER 64          // i's staged per super-tile in k_msg
#define FSTRIDE 72        // bf16 row stride for F_lds (64 + 8 pad)
#define QSPL 4            // i-range splits per j in k_msg

typedef __attribute__((ext_vector_type(8))) short short8;
typedef __attribute__((ext_vector_type(4))) float float4v;

__device__ __forceinline__ float silu_f(float v) {
    return v / (1.0f + __expf(-v));
}

__device__ __forceinline__ unsigned short f2bf(float f) {
    unsigned int u = __float_as_uint(f);
    unsigned int r = (u + 0x7FFFu + ((u >> 16) & 1u)) >> 16;  // RNE
    return (unsigned short)r;
}

// x[i,h] = embed[clip(an[i])]; a[i,h] = b1[h] + x[i,:] @ Wx[:,h]
__global__ __launch_bounds__(H) void k_embed_lin(const int* __restrict__ an,
                                                 const float* __restrict__ embed,
                                                 const float* __restrict__ wx,
                                                 const float* __restrict__ b1,
                                                 float* __restrict__ x,
                                                 float* __restrict__ a) {
    int i = blockIdx.x, h = threadIdx.x;
    __shared__ float xs[H];
    int z = an[i];
    z = min(max(z, 0), 99);
    float xv = embed[z * H + h];
    x[i * H + h] = xv;
    xs[h] = xv;
    __syncthreads();
    float a0 = b1[h], a1 = 0.f, a2 = 0.f, a3 = 0.f;
#pragma unroll 8
    for (int k = 0; k < H; k += 4) {
        a0 += xs[k]     * wx[(k)     * H + h];
        a1 += xs[k + 1] * wx[(k + 1) * H + h];
        a2 += xs[k + 2] * wx[(k + 2) * H + h];
        a3 += xs[k + 3] * wx[(k + 3) * H + h];
    }
    a[i * H + h] = (a0 + a1) + (a2 + a3);
}

// MFMA message kernel. Block = (j, i-quarter). Grid = QSPL*N. 256 threads (4 waves).
// msum4[q, j, h] = sum_{i in quarter q} valid(i,j) * silu( a[i,h] + F_ij[0:53] @ wfeat[0:53,h] )
// __launch_bounds__(256, 8): force VGPR<=64 so 8 blocks/CU fit (R4 was 68 -> 7 waves/SIMD).
__global__ __launch_bounds__(256, 8) void k_msg(const float* __restrict__ a,
                                                const float* __restrict__ pos,
                                                const float* __restrict__ wfeat,
                                                float* __restrict__ msum4,
                                                int* __restrict__ cnt4) {
    int bx = blockIdx.x;
    int j = bx >> 2;
    int q = bx & (QSPL - 1);
    int tid = threadIdx.x;
    int lane = tid & 63;
    int wv = tid >> 6;        // wave 0..3
    int nn = lane & 15;       // tile column
    int quad = lane >> 4;     // 0..3

    __shared__ unsigned short F[SUPER * FSTRIDE];  // bf16 features
    __shared__ float validf[SUPER];
    __shared__ int cnt_sh;

    if (tid == 0) cnt_sh = 0;

    float pjx = pos[j * 3 + 0], pjy = pos[j * 3 + 1], pjz = pos[j * 3 + 2];

    // B fragments: loop-invariant. B[k = 32c + quad*8+jj][n = hbase + 16t + nn]
    int hbase = wv * 32;
    short8 bfrag[2][2];
    for (int c = 0; c < 2; c++) {
        for (int t = 0; t < 2; t++) {
            short8 b;
            int h = hbase + 16 * t + nn;
#pragma unroll
            for (int jj = 0; jj < 8; jj++) {
                int k = c * 32 + quad * 8 + jj;
                float v = (k < NUM_RBF + 3) ? wfeat[k * H + h] : 0.0f;
                b[jj] = (short)f2bf(v);
            }
            bfrag[c][t] = b;
        }
    }

    const float DELTA = 5.0f / 49.0f;
    float pacc0 = 0.0f, pacc1 = 0.0f;

    const int SPQ = N / SUPER / QSPL;   // supertiles per quarter (2)
    for (int s = q * SPQ; s < (q + 1) * SPQ; s++) {
        __syncthreads();   // protect F/validf from previous iteration's readers
        {
            // stage features: thread t -> i_local = t>>2, k strip = (t&3)*16 .. +16
            int il = tid >> 2;
            int kb = (tid & 3) * 16;
            int i = s * SUPER + il;
            float dx = pos[i * 3 + 0] - pjx;
            float dy = pos[i * 3 + 1] - pjy;
            float dz = pos[i * 3 + 2] - pjz;
            float d = sqrtf(dx * dx + dy * dy + dz * dz);
            float rinv = 1.0f / fmaxf(d, 1e-8f);
            unsigned short vals[16];
#pragma unroll
            for (int qq = 0; qq < 16; qq++) {
                int k = kb + qq;
                float v;
                if (k < NUM_RBF) {
                    float tt = d - (float)k * DELTA;
                    v = __expf(-50.0f * tt * tt);      // 1/(2*0.1^2) = 50
                } else if (k == NUM_RBF)     v = dx * rinv;
                else if (k == NUM_RBF + 1)   v = dy * rinv;
                else if (k == NUM_RBF + 2)   v = dz * rinv;
                else                         v = 0.0f;
                vals[qq] = f2bf(v);
            }
            unsigned int* dst = (unsigned int*)&F[il * FSTRIDE + kb];
#pragma unroll
            for (int qq = 0; qq < 8; qq++)
                dst[qq] = (unsigned int)vals[2 * qq] | ((unsigned int)vals[2 * qq + 1] << 16);
            int v = (d < 5.0f) && (i != j);
            if ((tid & 3) == 0) validf[il] = (float)v;
            unsigned long long bal = __ballot(((lane & 3) == 0) && v);
            if (lane == 0) atomicAdd(&cnt_sh, __popcll(bal));
        }
        __syncthreads();

#pragma unroll
        for (int it = 0; it < SUPER / 16; it++) {
            int ibase = s * SUPER + it * 16 + quad * 4;
            // a-values loaded early; consumed only AFTER the MFMAs (epilogue add),
            // so the loads overlap MFMA execution instead of gating it.
            float av0[4], av1[4];
#pragma unroll
            for (int r = 0; r < 4; r++) {
                av0[r] = a[(ibase + r) * H + hbase + nn];
                av1[r] = a[(ibase + r) * H + hbase + 16 + nn];
            }
            // A frags: A[m = lane&15][k = 32c + quad*8 + jj]
            short8 afrag0 = *(const short8*)&F[(it * 16 + nn) * FSTRIDE + 0 * 32 + quad * 8];
            short8 afrag1 = *(const short8*)&F[(it * 16 + nn) * FSTRIDE + 1 * 32 + quad * 8];
            float4v acc0 = {0.0f, 0.0f, 0.0f, 0.0f};
            float4v acc1 = {0.0f, 0.0f, 0.0f, 0.0f};
            acc0 = __builtin_amdgcn_mfma_f32_16x16x32_bf16(afrag0, bfrag[0][0], acc0, 0, 0, 0);
            acc0 = __builtin_amdgcn_mfma_f32_16x16x32_bf16(afrag1, bfrag[1][0], acc0, 0, 0, 0);
            acc1 = __builtin_amdgcn_mfma_f32_16x16x32_bf16(afrag0, bfrag[0][1], acc1, 0, 0, 0);
            acc1 = __builtin_amdgcn_mfma_f32_16x16x32_bf16(afrag1, bfrag[1][1], acc1, 0, 0, 0);
            float4v vm4 = *(const float4v*)&validf[it * 16 + quad * 4];
#pragma unroll
            for (int r = 0; r < 4; r++) {
                pacc0 += vm4[r] * silu_f(acc0[r] + av0[r]);
                pacc1 += vm4[r] * silu_f(acc1[r] + av1[r]);
            }
        }
    }

    // reduce partials over quads (lanes nn, nn+16, nn+32, nn+48 share a column)
    pacc0 += __shfl_xor(pacc0, 16, 64);
    pacc0 += __shfl_xor(pacc0, 32, 64);
    pacc1 += __shfl_xor(pacc1, 16, 64);
    pacc1 += __shfl_xor(pacc1, 32, 64);
    if (lane < 16) {
        msum4[(q * N + j) * H + hbase + nn]      = pacc0;
        msum4[(q * N + j) * H + hbase + 16 + nn] = pacc1;
    }
    if (tid == 0) cnt4[q * N + j] = cnt_sh;
}

// 4-way split-K update: 512 threads = 4 groups of 128.
__global__ __launch_bounds__(512) void k_update(const float* __restrict__ msum4,
                                                const int* __restrict__ cnt4,
                                                const float* __restrict__ w2,
                                                const float* __restrict__ b2,
                                                const float* __restrict__ u1,
                                                const float* __restrict__ ub1,
                                                const float* __restrict__ u2,
                                                const float* __restrict__ ub2,
                                                float* __restrict__ x,
                                                const float* __restrict__ wxn,
                                                const float* __restrict__ b1n,
                                                float* __restrict__ a_next) {
    int j = blockIdx.x;
    int h = threadIdx.x & 127;
    int grp = threadIdx.x >> 7;   // 0..3

    __shared__ float sj[H], xj[H], ag[H], hid[H], xn[H];
    __shared__ float part[4][H];

    if (grp == 0) {
        xj[h] = x[j * H + h];
    } else if (grp == 1) {
        sj[h] = msum4[j * H + h] + msum4[(N + j) * H + h]
              + msum4[(2 * N + j) * H + h] + msum4[(3 * N + j) * H + h];
    }
    int c = cnt4[j] + cnt4[N + j] + cnt4[2 * N + j] + cnt4[3 * N + j];
    __syncthreads();

    {
        float p0 = 0.f, p1 = 0.f, p2 = 0.f, p3 = 0.f;
        int k0 = grp * 32;
#pragma unroll 8
        for (int k = 0; k < 32; k += 4) {
            p0 += sj[k0 + k]     * w2[(k0 + k)     * H + h];
            p1 += sj[k0 + k + 1] * w2[(k0 + k + 1) * H + h];
            p2 += sj[k0 + k + 2] * w2[(k0 + k + 2) * H + h];
            p3 += sj[k0 + k + 3] * w2[(k0 + k + 3) * H + h];
        }
        part[grp][h] = (p0 + p1) + (p2 + p3);
    }
    __syncthreads();
    if (grp == 0) ag[h] = part[0][h] + part[1][h] + part[2][h] + part[3][h] + (float)c * b2[h];
    __syncthreads();

    {
        const float* src = (grp < 2) ? xj : ag;
        int sbase = (grp & 1) * 64;
        int k0 = grp * 64;
        float p0 = 0.f, p1 = 0.f, p2 = 0.f, p3 = 0.f;
#pragma unroll 8
        for (int k = 0; k < 64; k += 4) {
            p0 += src[sbase + k]     * u1[(k0 + k)     * H + h];
            p1 += src[sbase + k + 1] * u1[(k0 + k + 1) * H + h];
            p2 += src[sbase + k + 2] * u1[(k0 + k + 2) * H + h];
            p3 += src[sbase + k + 3] * u1[(k0 + k + 3) * H + h];
        }
        part[grp][h] = (p0 + p1) + (p2 + p3);
    }
    __syncthreads();
    if (grp == 0) hid[h] = silu_f(part[0][h] + part[1][h] + part[2][h] + part[3][h] + ub1[h]);
    __syncthreads();

    {
        float p0 = 0.f, p1 = 0.f, p2 = 0.f, p3 = 0.f;
        int k0 = grp * 32;
#pragma unroll 8
        for (int k = 0; k < 32; k += 4) {
            p0 += hid[k0 + k]     * u2[(k0 + k)     * H + h];
            p1 += hid[k0 + k + 1] * u2[(k0 + k + 1) * H + h];
            p2 += hid[k0 + k + 2] * u2[(k0 + k + 2) * H + h];
            p3 += hid[k0 + k + 3] * u2[(k0 + k + 3) * H + h];
        }
        part[grp][h] = (p0 + p1) + (p2 + p3);
    }
    __syncthreads();
    if (grp == 0) {
        float xv = xj[h] + part[0][h] + part[1][h] + part[2][h] + part[3][h] + ub2[h];
        x[j * H + h] = xv;
        xn[h] = xv;
    }

    if (a_next != nullptr) {
        __syncthreads();
        float p0 = 0.f, p1 = 0.f, p2 = 0.f, p3 = 0.f;
        int k0 = grp * 32;
#pragma unroll 8
        for (int k = 0; k < 32; k += 4) {
            p0 += xn[k0 + k]     * wxn[(k0 + k)     * H + h];
            p1 += xn[k0 + k + 1] * wxn[(k0 + k + 1) * H + h];
            p2 += xn[k0 + k + 2] * wxn[(k0 + k + 2) * H + h];
            p3 += xn[k0 + k + 3] * wxn[(k0 + k + 3) * H + h];
        }
        part[grp][h] = (p0 + p1) + (p2 + p3);
        __syncthreads();
        if (grp == 0)
            a_next[j * H + h] = part[0][h] + part[1][h] + part[2][h] + part[3][h] + b1n[h];
    }
}

// per-molecule mean pool + 2-layer output MLP. batch is SORTED (reference does
// jnp.sort), so binary-search the [lo,hi) row range per molecule instead of
// scanning all N rows (serial 256-iteration latency chain in the old version).
__global__ __launch_bounds__(H) void k_pool(const float* __restrict__ x,
                                            const int* __restrict__ batch,
                                            const float* __restrict__ ow1,
                                            const float* __restrict__ ob1,
                                            const float* __restrict__ ow2,
                                            const float* __restrict__ ob2,
                                            float* __restrict__ out) {
    int m = blockIdx.x;
    int h = threadIdx.x;
    __shared__ int lo_s, hi_s;
    __shared__ float pooled[H];
    __shared__ float hid[H / 2];

    if (h == 0) {
        int a = 0, b = N;
        while (a < b) { int mid = (a + b) >> 1; if (batch[mid] < m) a = mid + 1; else b = mid; }
        lo_s = a;
        b = N;
        while (a < b) { int mid = (a + b) >> 1; if (batch[mid] < m + 1) a = mid + 1; else b = mid; }
        hi_s = a;
    }
    __syncthreads();

    int lo = lo_s, hi = hi_s;
    float s = 0.0f;
    for (int i = lo; i < hi; i++) s += x[i * H + h];
    pooled[h] = s / (float)max(hi - lo, 1);
    __syncthreads();

    if (h < H / 2) {
        float p0 = 0.f, p1 = 0.f;
        for (int k = 0; k < H; k += 2) {
            p0 += pooled[k]     * ow1[(k)     * (H / 2) + h];
            p1 += pooled[k + 1] * ow1[(k + 1) * (H / 2) + h];
        }
        hid[h] = silu_f(p0 + p1 + ob1[h]);
    }
    __syncthreads();

    if (h == 0) {
        float o = ob2[0];
        for (int k = 0; k < H / 2; k++) o += hid[k] * ow2[k];
        out[m] = o;
    }
}

extern "C" void kernel_launch(void* const* d_in, const int* in_sizes, int n_in,
                              void* d_out, int out_size, void* d_ws, size_t ws_size,
                              hipStream_t stream) {
    const int*   an      = (const int*)d_in[0];
    const float* pos     = (const float*)d_in[1];
    const int*   batch   = (const int*)d_in[2];
    const float* embed   = (const float*)d_in[3];
    const float* msg_w1  = (const float*)d_in[4];   // L x 181 x 128
    const float* msg_b1  = (const float*)d_in[5];
    const float* msg_w2  = (const float*)d_in[6];   // L x 128 x 128
    const float* msg_b2  = (const float*)d_in[7];
    const float* upd_w1  = (const float*)d_in[8];   // L x 256 x 128
    const float* upd_b1  = (const float*)d_in[9];
    const float* upd_w2  = (const float*)d_in[10];  // L x 128 x 128
    const float* upd_b2  = (const float*)d_in[11];
    const float* out_w1  = (const float*)d_in[12];  // 128 x 64
    const float* out_b1  = (const float*)d_in[13];
    const float* out_w2  = (const float*)d_in[14];  // 64 x 1
    const float* out_b2  = (const float*)d_in[15];
    float* out = (float*)d_out;

    float* x     = (float*)d_ws;        // N*H
    float* a     = x + N * H;           // N*H
    float* msum4 = a + N * H;           // QSPL*N*H
    int*   cnt4  = (int*)(msum4 + QSPL * N * H);  // QSPL*N

    const int W1ROWS = H + NUM_RBF + 3;  // 181

    k_embed_lin<<<N, H, 0, stream>>>(an, embed, msg_w1, msg_b1, x, a);
    for (int l = 0; l < L; l++) {
        k_msg<<<QSPL * N, 256, 0, stream>>>(a, pos, msg_w1 + l * W1ROWS * H + H * H,
                                            msum4, cnt4);
        const float* wxn = (l + 1 < L) ? (msg_w1 + (l + 1) * W1ROWS * H) : nullptr;
        const float* b1n = (l + 1 < L) ? (msg_b1 + (l + 1) * H) : nullptr;
        float* an_ = (l + 1 < L) ? a : nullptr;
        k_update<<<N, 512, 0, stream>>>(msum4, cnt4,
                                        msg_w2 + l * H * H, msg_b2 + l * H,
                                        upd_w1 + l * 2 * H * H, upd_b1 + l * H,
                                        upd_w2 + l * H * H, upd_b2 + l * H, x,
                                        wxn, b1n, an_);
    }
    k_pool<<<NMOL, H, 0, stream>>>(x, batch, out_w1, out_b1, out_w2, out_b2, out);
}

// Round 8
// 243.541 us; speedup vs baseline: 1.8319x; 1.8319x over previous
//
#include <hip/hip_runtime.h>
#include <math.h>

#define N 512
#define H 128
#define L 4
#define NUM_RBF 50
#define NMOL 16
#define SUPER 64          // i's staged per super-tile in k_msg
#define FSTRIDE 72        // bf16 row stride for F_lds (64 + 8 pad)
#define QSPL 4            // i-range splits per j in k_msg

typedef __attribute__((ext_vector_type(8))) short short8;
typedef __attribute__((ext_vector_type(4))) float float4v;

__device__ __forceinline__ float silu_f(float v) {
    return v / (1.0f + __expf(-v));
}

__device__ __forceinline__ unsigned short f2bf(float f) {
    unsigned int u = __float_as_uint(f);
    unsigned int r = (u + 0x7FFFu + ((u >> 16) & 1u)) >> 16;  // RNE
    return (unsigned short)r;
}

// x[i,h] = embed[clip(an[i])]; a[i,h] = b1[h] + x[i,:] @ Wx[:,h]
__global__ __launch_bounds__(H) void k_embed_lin(const int* __restrict__ an,
                                                 const float* __restrict__ embed,
                                                 const float* __restrict__ wx,
                                                 const float* __restrict__ b1,
                                                 float* __restrict__ x,
                                                 float* __restrict__ a) {
    int i = blockIdx.x, h = threadIdx.x;
    __shared__ float xs[H];
    int z = an[i];
    z = min(max(z, 0), 99);
    float xv = embed[z * H + h];
    x[i * H + h] = xv;
    xs[h] = xv;
    __syncthreads();
    float a0 = b1[h], a1 = 0.f, a2 = 0.f, a3 = 0.f;
#pragma unroll 8
    for (int k = 0; k < H; k += 4) {
        a0 += xs[k]     * wx[(k)     * H + h];
        a1 += xs[k + 1] * wx[(k + 1) * H + h];
        a2 += xs[k + 2] * wx[(k + 2) * H + h];
        a3 += xs[k + 3] * wx[(k + 3) * H + h];
    }
    a[i * H + h] = (a0 + a1) + (a2 + a3);
}

// MFMA message kernel. Block = (j, i-quarter). Grid = QSPL*N. 256 threads (4 waves).
// msum4[q, j, h] = sum_{i in quarter q} valid(i,j) * silu( a[i,h] + F_ij[0:53] @ wfeat[0:53,h] )
// NOTE: no min-waves launch_bounds arg — R7's (256,8) forced VGPR<=64 and the
// compiler spilled to scratch (155 MB FETCH/dispatch, 4x slower). Natural VGPR=68.
__global__ __launch_bounds__(256) void k_msg(const float* __restrict__ a,
                                             const float* __restrict__ pos,
                                             const float* __restrict__ wfeat,
                                             float* __restrict__ msum4,
                                             int* __restrict__ cnt4) {
    int bx = blockIdx.x;
    int j = bx >> 2;
    int q = bx & (QSPL - 1);
    int tid = threadIdx.x;
    int lane = tid & 63;
    int wv = tid >> 6;        // wave 0..3
    int nn = lane & 15;       // tile column
    int quad = lane >> 4;     // 0..3

    __shared__ unsigned short F[SUPER * FSTRIDE];  // bf16 features
    __shared__ float validf[SUPER];
    __shared__ int cnt_sh;

    if (tid == 0) cnt_sh = 0;

    float pjx = pos[j * 3 + 0], pjy = pos[j * 3 + 1], pjz = pos[j * 3 + 2];

    // B fragments: loop-invariant. B[k = 32c + quad*8+jj][n = hbase + 16t + nn]
    int hbase = wv * 32;
    short8 bfrag[2][2];
    for (int c = 0; c < 2; c++) {
        for (int t = 0; t < 2; t++) {
            short8 b;
            int h = hbase + 16 * t + nn;
#pragma unroll
            for (int jj = 0; jj < 8; jj++) {
                int k = c * 32 + quad * 8 + jj;
                float v = (k < NUM_RBF + 3) ? wfeat[k * H + h] : 0.0f;
                b[jj] = (short)f2bf(v);
            }
            bfrag[c][t] = b;
        }
    }

    const float DELTA = 5.0f / 49.0f;
    float pacc0 = 0.0f, pacc1 = 0.0f;

    const int SPQ = N / SUPER / QSPL;   // supertiles per quarter (2)
    for (int s = q * SPQ; s < (q + 1) * SPQ; s++) {
        __syncthreads();   // protect F/validf from previous iteration's readers
        {
            // stage features: thread t -> i_local = t>>2, k strip = (t&3)*16 .. +16
            int il = tid >> 2;
            int kb = (tid & 3) * 16;
            int i = s * SUPER + il;
            float dx = pos[i * 3 + 0] - pjx;
            float dy = pos[i * 3 + 1] - pjy;
            float dz = pos[i * 3 + 2] - pjz;
            float d = sqrtf(dx * dx + dy * dy + dz * dz);
            float rinv = 1.0f / fmaxf(d, 1e-8f);
            unsigned short vals[16];
#pragma unroll
            for (int qq = 0; qq < 16; qq++) {
                int k = kb + qq;
                float v;
                if (k < NUM_RBF) {
                    float tt = d - (float)k * DELTA;
                    v = __expf(-50.0f * tt * tt);      // 1/(2*0.1^2) = 50
                } else if (k == NUM_RBF)     v = dx * rinv;
                else if (k == NUM_RBF + 1)   v = dy * rinv;
                else if (k == NUM_RBF + 2)   v = dz * rinv;
                else                         v = 0.0f;
                vals[qq] = f2bf(v);
            }
            unsigned int* dst = (unsigned int*)&F[il * FSTRIDE + kb];
#pragma unroll
            for (int qq = 0; qq < 8; qq++)
                dst[qq] = (unsigned int)vals[2 * qq] | ((unsigned int)vals[2 * qq + 1] << 16);
            int v = (d < 5.0f) && (i != j);
            if ((tid & 3) == 0) validf[il] = (float)v;
            unsigned long long bal = __ballot(((lane & 3) == 0) && v);
            if (lane == 0) atomicAdd(&cnt_sh, __popcll(bal));
        }
        __syncthreads();

#pragma unroll
        for (int it = 0; it < SUPER / 16; it++) {
            int ibase = s * SUPER + it * 16 + quad * 4;
            // a-values loaded early; consumed only AFTER the MFMAs (epilogue add),
            // so the loads overlap MFMA execution instead of gating it.
            float av0[4], av1[4];
#pragma unroll
            for (int r = 0; r < 4; r++) {
                av0[r] = a[(ibase + r) * H + hbase + nn];
                av1[r] = a[(ibase + r) * H + hbase + 16 + nn];
            }
            // A frags: A[m = lane&15][k = 32c + quad*8 + jj]
            short8 afrag0 = *(const short8*)&F[(it * 16 + nn) * FSTRIDE + 0 * 32 + quad * 8];
            short8 afrag1 = *(const short8*)&F[(it * 16 + nn) * FSTRIDE + 1 * 32 + quad * 8];
            float4v acc0 = {0.0f, 0.0f, 0.0f, 0.0f};
            float4v acc1 = {0.0f, 0.0f, 0.0f, 0.0f};
            acc0 = __builtin_amdgcn_mfma_f32_16x16x32_bf16(afrag0, bfrag[0][0], acc0, 0, 0, 0);
            acc0 = __builtin_amdgcn_mfma_f32_16x16x32_bf16(afrag1, bfrag[1][0], acc0, 0, 0, 0);
            acc1 = __builtin_amdgcn_mfma_f32_16x16x32_bf16(afrag0, bfrag[0][1], acc1, 0, 0, 0);
            acc1 = __builtin_amdgcn_mfma_f32_16x16x32_bf16(afrag1, bfrag[1][1], acc1, 0, 0, 0);
            float4v vm4 = *(const float4v*)&validf[it * 16 + quad * 4];
#pragma unroll
            for (int r = 0; r < 4; r++) {
                pacc0 += vm4[r] * silu_f(acc0[r] + av0[r]);
                pacc1 += vm4[r] * silu_f(acc1[r] + av1[r]);
            }
        }
    }

    // reduce partials over quads (lanes nn, nn+16, nn+32, nn+48 share a column)
    pacc0 += __shfl_xor(pacc0, 16, 64);
    pacc0 += __shfl_xor(pacc0, 32, 64);
    pacc1 += __shfl_xor(pacc1, 16, 64);
    pacc1 += __shfl_xor(pacc1, 32, 64);
    if (lane < 16) {
        msum4[(q * N + j) * H + hbase + nn]      = pacc0;
        msum4[(q * N + j) * H + hbase + 16 + nn] = pacc1;
    }
    if (tid == 0) cnt4[q * N + j] = cnt_sh;
}

// 4-way split-K update: 512 threads = 4 groups of 128.
__global__ __launch_bounds__(512) void k_update(const float* __restrict__ msum4,
                                                const int* __restrict__ cnt4,
                                                const float* __restrict__ w2,
                                                const float* __restrict__ b2,
                                                const float* __restrict__ u1,
                                                const float* __restrict__ ub1,
                                                const float* __restrict__ u2,
                                                const float* __restrict__ ub2,
                                                float* __restrict__ x,
                                                const float* __restrict__ wxn,
                                                const float* __restrict__ b1n,
                                                float* __restrict__ a_next) {
    int j = blockIdx.x;
    int h = threadIdx.x & 127;
    int grp = threadIdx.x >> 7;   // 0..3

    __shared__ float sj[H], xj[H], ag[H], hid[H], xn[H];
    __shared__ float part[4][H];

    if (grp == 0) {
        xj[h] = x[j * H + h];
    } else if (grp == 1) {
        sj[h] = msum4[j * H + h] + msum4[(N + j) * H + h]
              + msum4[(2 * N + j) * H + h] + msum4[(3 * N + j) * H + h];
    }
    int c = cnt4[j] + cnt4[N + j] + cnt4[2 * N + j] + cnt4[3 * N + j];
    __syncthreads();

    {
        float p0 = 0.f, p1 = 0.f, p2 = 0.f, p3 = 0.f;
        int k0 = grp * 32;
#pragma unroll 8
        for (int k = 0; k < 32; k += 4) {
            p0 += sj[k0 + k]     * w2[(k0 + k)     * H + h];
            p1 += sj[k0 + k + 1] * w2[(k0 + k + 1) * H + h];
            p2 += sj[k0 + k + 2] * w2[(k0 + k + 2) * H + h];
            p3 += sj[k0 + k + 3] * w2[(k0 + k + 3) * H + h];
        }
        part[grp][h] = (p0 + p1) + (p2 + p3);
    }
    __syncthreads();
    if (grp == 0) ag[h] = part[0][h] + part[1][h] + part[2][h] + part[3][h] + (float)c * b2[h];
    __syncthreads();

    {
        const float* src = (grp < 2) ? xj : ag;
        int sbase = (grp & 1) * 64;
        int k0 = grp * 64;
        float p0 = 0.f, p1 = 0.f, p2 = 0.f, p3 = 0.f;
#pragma unroll 8
        for (int k = 0; k < 64; k += 4) {
            p0 += src[sbase + k]     * u1[(k0 + k)     * H + h];
            p1 += src[sbase + k + 1] * u1[(k0 + k + 1) * H + h];
            p2 += src[sbase + k + 2] * u1[(k0 + k + 2) * H + h];
            p3 += src[sbase + k + 3] * u1[(k0 + k + 3) * H + h];
        }
        part[grp][h] = (p0 + p1) + (p2 + p3);
    }
    __syncthreads();
    if (grp == 0) hid[h] = silu_f(part[0][h] + part[1][h] + part[2][h] + part[3][h] + ub1[h]);
    __syncthreads();

    {
        float p0 = 0.f, p1 = 0.f, p2 = 0.f, p3 = 0.f;
        int k0 = grp * 32;
#pragma unroll 8
        for (int k = 0; k < 32; k += 4) {
            p0 += hid[k0 + k]     * u2[(k0 + k)     * H + h];
            p1 += hid[k0 + k + 1] * u2[(k0 + k + 1) * H + h];
            p2 += hid[k0 + k + 2] * u2[(k0 + k + 2) * H + h];
            p3 += hid[k0 + k + 3] * u2[(k0 + k + 3) * H + h];
        }
        part[grp][h] = (p0 + p1) + (p2 + p3);
    }
    __syncthreads();
    if (grp == 0) {
        float xv = xj[h] + part[0][h] + part[1][h] + part[2][h] + part[3][h] + ub2[h];
        x[j * H + h] = xv;
        xn[h] = xv;
    }

    if (a_next != nullptr) {
        __syncthreads();
        float p0 = 0.f, p1 = 0.f, p2 = 0.f, p3 = 0.f;
        int k0 = grp * 32;
#pragma unroll 8
        for (int k = 0; k < 32; k += 4) {
            p0 += xn[k0 + k]     * wxn[(k0 + k)     * H + h];
            p1 += xn[k0 + k + 1] * wxn[(k0 + k + 1) * H + h];
            p2 += xn[k0 + k + 2] * wxn[(k0 + k + 2) * H + h];
            p3 += xn[k0 + k + 3] * wxn[(k0 + k + 3) * H + h];
        }
        part[grp][h] = (p0 + p1) + (p2 + p3);
        __syncthreads();
        if (grp == 0)
            a_next[j * H + h] = part[0][h] + part[1][h] + part[2][h] + part[3][h] + b1n[h];
    }
}

// per-molecule mean pool + 2-layer output MLP. batch is SORTED (reference does
// jnp.sort), so binary-search the [lo,hi) row range per molecule instead of
// scanning all N rows.
__global__ __launch_bounds__(H) void k_pool(const float* __restrict__ x,
                                            const int* __restrict__ batch,
                                            const float* __restrict__ ow1,
                                            const float* __restrict__ ob1,
                                            const float* __restrict__ ow2,
                                            const float* __restrict__ ob2,
                                            float* __restrict__ out) {
    int m = blockIdx.x;
    int h = threadIdx.x;
    __shared__ int lo_s, hi_s;
    __shared__ float pooled[H];
    __shared__ float hid[H / 2];

    if (h == 0) {
        int a = 0, b = N;
        while (a < b) { int mid = (a + b) >> 1; if (batch[mid] < m) a = mid + 1; else b = mid; }
        lo_s = a;
        b = N;
        while (a < b) { int mid = (a + b) >> 1; if (batch[mid] < m + 1) a = mid + 1; else b = mid; }
        hi_s = a;
    }
    __syncthreads();

    int lo = lo_s, hi = hi_s;
    float s = 0.0f;
    for (int i = lo; i < hi; i++) s += x[i * H + h];
    pooled[h] = s / (float)max(hi - lo, 1);
    __syncthreads();

    if (h < H / 2) {
        float p0 = 0.f, p1 = 0.f;
        for (int k = 0; k < H; k += 2) {
            p0 += pooled[k]     * ow1[(k)     * (H / 2) + h];
            p1 += pooled[k + 1] * ow1[(k + 1) * (H / 2) + h];
        }
        hid[h] = silu_f(p0 + p1 + ob1[h]);
    }
    __syncthreads();

    if (h == 0) {
        float o = ob2[0];
        for (int k = 0; k < H / 2; k++) o += hid[k] * ow2[k];
        out[m] = o;
    }
}

extern "C" void kernel_launch(void* const* d_in, const int* in_sizes, int n_in,
                              void* d_out, int out_size, void* d_ws, size_t ws_size,
                              hipStream_t stream) {
    const int*   an      = (const int*)d_in[0];
    const float* pos     = (const float*)d_in[1];
    const int*   batch   = (const int*)d_in[2];
    const float* embed   = (const float*)d_in[3];
    const float* msg_w1  = (const float*)d_in[4];   // L x 181 x 128
    const float* msg_b1  = (const float*)d_in[5];
    const float* msg_w2  = (const float*)d_in[6];   // L x 128 x 128
    const float* msg_b2  = (const float*)d_in[7];
    const float* upd_w1  = (const float*)d_in[8];   // L x 256 x 128
    const float* upd_b1  = (const float*)d_in[9];
    const float* upd_w2  = (const float*)d_in[10];  // L x 128 x 128
    const float* upd_b2  = (const float*)d_in[11];
    const float* out_w1  = (const float*)d_in[12];  // 128 x 64
    const float* out_b1  = (const float*)d_in[13];
    const float* out_w2  = (const float*)d_in[14];  // 64 x 1
    const float* out_b2  = (const float*)d_in[15];
    float* out = (float*)d_out;

    float* x     = (float*)d_ws;        // N*H
    float* a     = x + N * H;           // N*H
    float* msum4 = a + N * H;           // QSPL*N*H
    int*   cnt4  = (int*)(msum4 + QSPL * N * H);  // QSPL*N

    const int W1ROWS = H + NUM_RBF + 3;  // 181

    k_embed_lin<<<N, H, 0, stream>>>(an, embed, msg_w1, msg_b1, x, a);
    for (int l = 0; l < L; l++) {
        k_msg<<<QSPL * N, 256, 0, stream>>>(a, pos, msg_w1 + l * W1ROWS * H + H * H,
                                            msum4, cnt4);
        const float* wxn = (l + 1 < L) ? (msg_w1 + (l + 1) * W1ROWS * H) : nullptr;
        const float* b1n = (l + 1 < L) ? (msg_b1 + (l + 1) * H) : nullptr;
        float* an_ = (l + 1 < L) ? a : nullptr;
        k_update<<<N, 512, 0, stream>>>(msum4, cnt4,
                                        msg_w2 + l * H * H, msg_b2 + l * H,
                                        upd_w1 + l * 2 * H * H, upd_b1 + l * H,
                                        upd_w2 + l * H * H, upd_b2 + l * H, x,
                                        wxn, b1n, an_);
    }
    k_pool<<<NMOL, H, 0, stream>>>(x, batch, out_w1, out_b1, out_w2, out_b2, out);
}